// Round 5
// baseline (1320.431 us; speedup 1.0000x reference)
//
#include <hip/hip_runtime.h>
#include <math.h>

// ULOSD keypoint autoencoder, fp32 direct convolutions.
// Round 5 (= round 4 fixed to compile): (a) explicit register double-buffer
// prefetch of next-ci inputs (raw loads issued before current FMA block;
// boundary masks applied at use), (b) split-K via blockIdx.z for grid-starved
// high-ratio layers (e5, e6, d1) with a combine epilogue for bias+activation.
// All CPT/KS branches are `if constexpr` so dead paths don't instantiate.

enum { ACT_ID = 0, ACT_LRELU = 1, ACT_SOFTPLUS = 2, ACT_RELU = 3 };

template<int ACT>
__device__ __forceinline__ float act_fn(float x) {
  if (ACT == ACT_LRELU)    return x >= 0.f ? x : 0.2f * x;
  if (ACT == ACT_SOFTPLUS) return fmaxf(x, 0.f) + log1pf(expf(-fabsf(x)));
  if (ACT == ACT_RELU)     return fmaxf(x, 0.f);
  return x;
}

// ---------------- stride-1 3x3 SAME conv, NC couts x CPT cols per thread -------
template<int ACT, int NC, int CPT, int KS>
__global__ __launch_bounds__(256)
void conv_s1(const float* __restrict__ in, const float* __restrict__ w,
             const float* __restrict__ bias, float* __restrict__ out,
             int Cin, int Cout, int H, int W, size_t kstride) {
  const int cogs = Cout / NC;
  const int gx  = blockIdx.x;
  const int cog = gx % cogs;
  const int b   = gx / cogs;
  const int co0 = cog * NC;
  const int Wq  = W / CPT;
  const int items = H * Wq;
  const int item  = blockIdx.y * 256 + threadIdx.x;
  if (item >= items) return;
  const int y  = item / Wq;
  const int x0 = (item - y * Wq) * CPT;

  const int HW = H * W;
  const float* ib = in + (size_t)b * Cin * HW;
  const int nci = Cin / KS;
  const int ci0 = (KS > 1) ? (int)blockIdx.z * nci : 0;
  const int ci1 = ci0 + nci;
  float* outbase = out + ((KS > 1) ? (size_t)blockIdx.z * kstride : 0);

  const bool okT = (y > 0), okB = (y < H - 1);
  const bool okL = (x0 > 0), okR = (x0 + CPT < W);
  const int ym = okT ? (y - 1) : 0;
  const int yp = okB ? (y + 1) : 0;
  const int xl = okL ? (x0 - 1) : 0;
  const int xr = okR ? (x0 + CPT) : 0;

  float acc[NC][CPT];
  #pragma unroll
  for (int u = 0; u < NC; ++u) {
    #pragma unroll
    for (int q = 0; q < CPT; ++q) acc[u][q] = 0.f;
  }

  constexpr int RV = CPT + 2;

  auto load_rows = [&](float* v, int ci) {
    const float* p = ib + ci * HW;
    #pragma unroll
    for (int dy = 0; dy < 3; ++dy) {
      const int ry = (dy == 0) ? ym : ((dy == 1) ? y : yp);
      const float* r = p + ry * W;
      float* o = v + dy * RV;
      o[0] = r[xl];
      if constexpr (CPT == 4) {
        float4 m = *(const float4*)(r + x0);
        o[1] = m.x; o[2] = m.y; o[3] = m.z; o[4] = m.w;
      } else if constexpr (CPT == 2) {
        float2 m = *(const float2*)(r + x0);
        o[1] = m.x; o[2] = m.y;
      } else {
        #pragma unroll
        for (int q = 0; q < CPT; ++q) o[1 + q] = r[x0 + q];
      }
      o[CPT + 1] = r[xr];
    }
  };

  auto fma_rows = [&](float* v, int ci) {
    #pragma unroll
    for (int dy = 0; dy < 3; ++dy) {
      const bool okRow = (dy == 0) ? okT : ((dy == 1) ? true : okB);
      float* o = v + dy * RV;
      o[0] = (okRow && okL) ? o[0] : 0.f;
      #pragma unroll
      for (int q = 1; q <= CPT; ++q) o[q] = okRow ? o[q] : 0.f;
      o[CPT + 1] = (okRow && okR) ? o[CPT + 1] : 0.f;
    }
    #pragma unroll
    for (int u = 0; u < NC; ++u) {
      const float* wp = w + ((size_t)(co0 + u) * Cin + ci) * 9;
      #pragma unroll
      for (int dy = 0; dy < 3; ++dy) {
        const float w0 = wp[dy*3], w1 = wp[dy*3+1], w2 = wp[dy*3+2];
        const float* o = v + dy * RV;
        #pragma unroll
        for (int q = 0; q < CPT; ++q)
          acc[u][q] += o[q] * w0 + o[q + 1] * w1 + o[q + 2] * w2;
      }
    }
  };

  float va[3 * RV], vb[3 * RV];
  load_rows(va, ci0);
  int ci = ci0;
  while (true) {
    if (ci + 1 < ci1) load_rows(vb, ci + 1);
    fma_rows(va, ci);
    ++ci; if (ci >= ci1) break;
    if (ci + 1 < ci1) load_rows(va, ci + 1);
    fma_rows(vb, ci);
    ++ci; if (ci >= ci1) break;
  }

  #pragma unroll
  for (int u = 0; u < NC; ++u) {
    float* op = outbase + ((size_t)(b * Cout + co0 + u) * H + y) * W + x0;
    if constexpr (KS > 1) {
      if constexpr (CPT == 4) {
        float4 r4 = {acc[u][0], acc[u][1], acc[u][2], acc[u][3]};
        *(float4*)op = r4;
      } else if constexpr (CPT == 2) {
        float2 r2 = {acc[u][0], acc[u][1]};
        *(float2*)op = r2;
      } else {
        #pragma unroll
        for (int q = 0; q < CPT; ++q) op[q] = acc[u][q];
      }
    } else {
      const float bv = bias[co0 + u];
      if constexpr (CPT == 4) {
        float4 r4;
        r4.x = act_fn<ACT>(acc[u][0] + bv); r4.y = act_fn<ACT>(acc[u][1] + bv);
        r4.z = act_fn<ACT>(acc[u][2] + bv); r4.w = act_fn<ACT>(acc[u][3] + bv);
        *(float4*)op = r4;
      } else if constexpr (CPT == 2) {
        float2 r2;
        r2.x = act_fn<ACT>(acc[u][0] + bv); r2.y = act_fn<ACT>(acc[u][1] + bv);
        *(float2*)op = r2;
      } else {
        #pragma unroll
        for (int q = 0; q < CPT; ++q) op[q] = act_fn<ACT>(acc[u][q] + bv);
      }
    }
  }
}

// ---------------- stride-2 3x3 SAME conv (pad_before=0, pad_after=1) -----------
template<int ACT, int NC, int CPT, int KS>
__global__ __launch_bounds__(256)
void conv_s2(const float* __restrict__ in, const float* __restrict__ w,
             const float* __restrict__ bias, float* __restrict__ out,
             int Cin, int Cout, int H, int W, size_t kstride) {
  const int Ho = H >> 1, Wo = W >> 1;
  const int cogs = Cout / NC;
  const int gx  = blockIdx.x;
  const int cog = gx % cogs;
  const int b   = gx / cogs;
  const int co0 = cog * NC;
  const int Wq  = Wo / CPT;
  const int items = Ho * Wq;
  const int item  = blockIdx.y * 256 + threadIdx.x;
  if (item >= items) return;
  const int y  = item / Wq;
  const int x0 = (item - y * Wq) * CPT;
  const int ix = 2 * x0;

  const int HW = H * W;
  const float* ib = in + (size_t)b * Cin * HW;
  const int nci = Cin / KS;
  const int ci0 = (KS > 1) ? (int)blockIdx.z * nci : 0;
  const int ci1 = ci0 + nci;
  float* outbase = out + ((KS > 1) ? (size_t)blockIdx.z * kstride : 0);

  const int iy0 = 2 * y, iy1 = 2 * y + 1, iy2 = 2 * y + 2;
  const bool okB = (iy2 < H);
  const int iy2c = okB ? iy2 : 0;
  const bool okR = (ix + 2 * CPT < W);
  const int ixr  = okR ? (ix + 2 * CPT) : 0;

  float acc[NC][CPT];
  #pragma unroll
  for (int u = 0; u < NC; ++u) {
    #pragma unroll
    for (int q = 0; q < CPT; ++q) acc[u][q] = 0.f;
  }

  constexpr int RV = 2 * CPT + 1;

  auto load_rows = [&](float* v, int ci) {
    const float* p = ib + ci * HW;
    #pragma unroll
    for (int dy = 0; dy < 3; ++dy) {
      const int ry = (dy == 0) ? iy0 : ((dy == 1) ? iy1 : iy2c);
      const float* r = p + ry * W;
      float* o = v + dy * RV;
      if constexpr (CPT == 4) {
        float4 m0 = *(const float4*)(r + ix);
        float4 m1 = *(const float4*)(r + ix + 4);
        o[0]=m0.x; o[1]=m0.y; o[2]=m0.z; o[3]=m0.w;
        o[4]=m1.x; o[5]=m1.y; o[6]=m1.z; o[7]=m1.w;
      } else if constexpr (CPT == 2) {
        float4 m0 = *(const float4*)(r + ix);
        o[0]=m0.x; o[1]=m0.y; o[2]=m0.z; o[3]=m0.w;
      } else {
        float2 m0 = *(const float2*)(r + ix);
        o[0]=m0.x; o[1]=m0.y;
      }
      o[2*CPT] = r[ixr];
    }
  };

  auto fma_rows = [&](float* v, int ci) {
    #pragma unroll
    for (int dy = 0; dy < 3; ++dy) {
      const bool okRow = (dy < 2) || okB;
      float* o = v + dy * RV;
      #pragma unroll
      for (int q = 0; q < 2 * CPT; ++q) o[q] = okRow ? o[q] : 0.f;
      o[2*CPT] = (okRow && okR) ? o[2*CPT] : 0.f;
    }
    #pragma unroll
    for (int u = 0; u < NC; ++u) {
      const float* wp = w + ((size_t)(co0 + u) * Cin + ci) * 9;
      #pragma unroll
      for (int dy = 0; dy < 3; ++dy) {
        const float w0 = wp[dy*3], w1 = wp[dy*3+1], w2 = wp[dy*3+2];
        const float* o = v + dy * RV;
        #pragma unroll
        for (int q = 0; q < CPT; ++q)
          acc[u][q] += o[2*q] * w0 + o[2*q + 1] * w1 + o[2*q + 2] * w2;
      }
    }
  };

  float va[3 * RV], vb[3 * RV];
  load_rows(va, ci0);
  int ci = ci0;
  while (true) {
    if (ci + 1 < ci1) load_rows(vb, ci + 1);
    fma_rows(va, ci);
    ++ci; if (ci >= ci1) break;
    if (ci + 1 < ci1) load_rows(va, ci + 1);
    fma_rows(vb, ci);
    ++ci; if (ci >= ci1) break;
  }

  #pragma unroll
  for (int u = 0; u < NC; ++u) {
    float* op = outbase + ((size_t)(b * Cout + co0 + u) * Ho + y) * Wo + x0;
    if constexpr (KS > 1) {
      if constexpr (CPT == 4) {
        float4 r4 = {acc[u][0], acc[u][1], acc[u][2], acc[u][3]};
        *(float4*)op = r4;
      } else if constexpr (CPT == 2) {
        float2 r2 = {acc[u][0], acc[u][1]};
        *(float2*)op = r2;
      } else {
        #pragma unroll
        for (int q = 0; q < CPT; ++q) op[q] = acc[u][q];
      }
    } else {
      const float bv = bias[co0 + u];
      if constexpr (CPT == 4) {
        float4 r4;
        r4.x = act_fn<ACT>(acc[u][0] + bv); r4.y = act_fn<ACT>(acc[u][1] + bv);
        r4.z = act_fn<ACT>(acc[u][2] + bv); r4.w = act_fn<ACT>(acc[u][3] + bv);
        *(float4*)op = r4;
      } else if constexpr (CPT == 2) {
        float2 r2;
        r2.x = act_fn<ACT>(acc[u][0] + bv); r2.y = act_fn<ACT>(acc[u][1] + bv);
        *(float2*)op = r2;
      } else {
        #pragma unroll
        for (int q = 0; q < CPT; ++q) op[q] = act_fn<ACT>(acc[u][q] + bv);
      }
    }
  }
}

// ---------------- stride-2 3x3 SAME transposed conv ----------------------------
template<int ACT, int NC>
__global__ __launch_bounds__(256)
void tconv(const float* __restrict__ in, const float* __restrict__ w,
           const float* __restrict__ bias, float* __restrict__ out,
           int Cin, int Cout, int Hin) {
  const int cogs = Cout / NC;
  const int gx  = blockIdx.x;
  const int cog = gx % cogs;
  const int b   = gx / cogs;
  const int co0 = cog * NC;
  const int items = Hin * Hin;
  const int item  = blockIdx.y * 256 + threadIdx.x;
  if (item >= items) return;
  const int i = item / Hin;
  const int j = item - i * Hin;

  const float* ib = in + (size_t)b * Cin * items;
  const bool okT = (i > 0), okL = (j > 0);
  const int im = okT ? i - 1 : 0;
  const int jm = okL ? j - 1 : 0;

  float a00[NC], a01[NC], a10[NC], a11[NC];
  #pragma unroll
  for (int u = 0; u < NC; ++u) { a00[u]=0.f; a01[u]=0.f; a10[u]=0.f; a11[u]=0.f; }

  auto load4 = [&](float* v, int ci) {
    const float* p = ib + ci * items;
    v[0] = p[im*Hin + jm];
    v[1] = p[im*Hin + j];
    v[2] = p[i*Hin + jm];
    v[3] = p[i*Hin + j];
  };
  auto fma4 = [&](float* v, int ci) {
    float xtl = (okT && okL) ? v[0] : 0.f;
    float xtr = okT ? v[1] : 0.f;
    float xbl = okL ? v[2] : 0.f;
    float xbr = v[3];
    #pragma unroll
    for (int u = 0; u < NC; ++u) {
      const float* wp = w + ((size_t)(co0 + u) * Cin + ci) * 9;
      const float w00 = wp[0], w01 = wp[1], w02 = wp[2];
      const float w10 = wp[3], w11 = wp[4], w12 = wp[5];
      const float w20 = wp[6], w21 = wp[7], w22 = wp[8];
      a00[u] += xtl*w00 + xtr*w02 + xbl*w20 + xbr*w22;
      a01[u] += xtr*w01 + xbr*w21;
      a10[u] += xbl*w10 + xbr*w12;
      a11[u] += xbr*w11;
    }
  };

  float va[4], vb[4];
  load4(va, 0);
  int ci = 0;
  while (true) {
    if (ci + 1 < Cin) load4(vb, ci + 1);
    fma4(va, ci);
    ++ci; if (ci >= Cin) break;
    if (ci + 1 < Cin) load4(va, ci + 1);
    fma4(vb, ci);
    ++ci; if (ci >= Cin) break;
  }

  const int Ho = Hin * 2;
  #pragma unroll
  for (int u = 0; u < NC; ++u) {
    const float bv = bias[co0 + u];
    float* op = out + (size_t)(b * Cout + co0 + u) * Ho * Ho + (2*i) * Ho + 2*j;
    float2 t0, t1;
    t0.x = act_fn<ACT>(a00[u] + bv); t0.y = act_fn<ACT>(a01[u] + bv);
    t1.x = act_fn<ACT>(a10[u] + bv); t1.y = act_fn<ACT>(a11[u] + bv);
    *(float2*)op = t0;
    *(float2*)(op + Ho) = t1;
  }
}

// ---------------- split-K combine: out = act(P0 + P1 + bias[c]) ----------------
template<int ACT>
__global__ __launch_bounds__(256)
void combine2(const float* __restrict__ P0, const float* __restrict__ P1,
              const float* __restrict__ bias, float* __restrict__ out,
              int C, int HW, int n4) {
  const int i = blockIdx.x * 256 + threadIdx.x;
  if (i >= n4) return;
  const int e = i * 4;
  const int c = (e / HW) % C;
  float4 a = ((const float4*)P0)[i];
  float4 b = ((const float4*)P1)[i];
  const float bv = bias[c];
  float4 r;
  r.x = act_fn<ACT>(a.x + b.x + bv);
  r.y = act_fn<ACT>(a.y + b.y + bv);
  r.z = act_fn<ACT>(a.z + b.z + bv);
  r.w = act_fn<ACT>(a.w + b.w + bv);
  ((float4*)out)[i] = r;
}

// ---------------- keypoint reductions ------------------------------------------
__global__ __launch_bounds__(64)
void kp_reduce(const float* __restrict__ R, float* __restrict__ S,
               float* __restrict__ Sh, float* __restrict__ Sw) {
  const int bk = blockIdx.x;
  const int t = threadIdx.x;
  const float* p = R + (size_t)bk * 256;
  float s = 0.f, sh = 0.f, sw = 0.f;
  #pragma unroll
  for (int q = 0; q < 4; ++q) {
    int idx = t + q * 64;
    float v = p[idx];
    s  += v;
    sh += v * (float)(idx >> 4);
    sw += v * (float)(idx & 15);
  }
  #pragma unroll
  for (int off = 32; off > 0; off >>= 1) {
    s  += __shfl_down(s, off);
    sh += __shfl_down(sh, off);
    sw += __shfl_down(sw, off);
  }
  if (t == 0) { S[bk] = s; Sh[bk] = sh; Sw[bk] = sw; }
}

__global__ __launch_bounds__(256)
void kp_maps(const float* __restrict__ S, const float* __restrict__ Sh,
             const float* __restrict__ Sw, float* __restrict__ maps, int K) {
  const int bk = blockIdx.x;
  const int b = bk / K;
  const int t = threadIdx.x;
  const float s   = S[bk];
  const float den = S[b * K + (K - 1)];
  const float mu  = s * (1.0f / 256.0f);
  const float c0  = Sh[bk] / den;
  const float c1  = Sw[bk] / den;
  const float u = (float)(t >> 4);
  const float v = (float)(t & 15);
  const float d2 = (u - c0) * (u - c0) + (v - c1) * (v - c1);
  maps[(size_t)bk * 256 + t] = mu * expf(-0.5f * d2);
}

extern "C" void kernel_launch(void* const* d_in, const int* in_sizes, int n_in,
                              void* d_out, int out_size, void* d_ws, size_t ws_size,
                              hipStream_t stream) {
  const int B = 32;  // 4 * 8
  const float* x = (const float*)d_in[0];
  const float* ew[7]; const float* eb[7];
  for (int j = 0; j < 7; ++j) { ew[j] = (const float*)d_in[1 + 2*j]; eb[j] = (const float*)d_in[2 + 2*j]; }
  const float* dw[6]; const float* db[6];
  for (int j = 0; j < 6; ++j) { dw[j] = (const float*)d_in[15 + 2*j]; db[j] = (const float*)d_in[16 + 2*j]; }

  float* ws   = (float*)d_ws;
  float* bufA = ws;                       // 16,777,216 floats
  float* bufB = bufA + 16777216;
  float* R    = bufB + 16777216;          // 1,048,576
  float* maps = R + 1048576;
  float* S    = maps + 1048576;           // 4096
  float* Sh   = S + 4096;
  float* Sw   = Sh + 4096;
  float* outp = (float*)d_out;

  dim3 blk(256);

  // ---- encoder ----
  conv_s1<ACT_ID,   8,4,1><<<dim3(B*4, 16),    blk, 0, stream>>>(x,    ew[0], eb[0], bufA, 3,   32,  128, 128, 0);
  conv_s1<ACT_ID,   8,4,1><<<dim3(B*4, 16),    blk, 0, stream>>>(bufA, ew[1], eb[1], bufB, 32,  32,  128, 128, 0);
  conv_s2<ACT_LRELU,8,4,1><<<dim3(B*8,  4),    blk, 0, stream>>>(bufB, ew[2], eb[2], bufA, 32,  64,  128, 128, 0);
  conv_s1<ACT_LRELU,8,4,1><<<dim3(B*8,  4),    blk, 0, stream>>>(bufA, ew[3], eb[3], bufB, 64,  64,  64,  64,  0);
  conv_s2<ACT_LRELU,8,2,1><<<dim3(B*16, 2),    blk, 0, stream>>>(bufB, ew[4], eb[4], bufA, 64,  128, 64,  64,  0);

  // e5: 128->128 @32x32, split-K=2 (1024 blocks), partials in dead bufA space
  float* P5 = bufA + 8388608;             // 2 x 4,194,304 floats
  conv_s1<ACT_LRELU,8,4,2><<<dim3(B*16, 1, 2), blk, 0, stream>>>(bufA, ew[5], eb[5], P5, 128, 128, 32, 32, 4194304);
  combine2<ACT_LRELU><<<dim3(4096), blk, 0, stream>>>(P5, P5 + 4194304, eb[5], bufB, 128, 1024, 1048576);

  // e6: 128->128 s2 @32->16, split-K=2 (1024 blocks), partials in bufA (dead)
  float* P6 = bufA;                       // 2 x 1,048,576 floats
  conv_s2<ACT_SOFTPLUS,8,1,2><<<dim3(B*16, 1, 2), blk, 0, stream>>>(bufB, ew[6], eb[6], P6, 128, 128, 32, 32, 1048576);
  combine2<ACT_SOFTPLUS><<<dim3(1024), blk, 0, stream>>>(P6, P6 + 1048576, eb[6], R, 128, 256, 262144);

  // ---- keypoint bottleneck ----
  kp_reduce<<<dim3(B*128), dim3(64), 0, stream>>>(R, S, Sh, Sw);
  kp_maps  <<<dim3(B*128), blk, 0, stream>>>(S, Sh, Sw, maps, 128);

  // ---- decoder ----
  tconv<ACT_RELU,2><<<dim3(B*32, 1), blk, 0, stream>>>(maps, dw[0], db[0], bufA, 128, 64, 16);

  // d1: 64->64 @32x32, split-K=2 (1024 blocks), partials in dead bufA space
  float* PD1 = bufA + 4194304;            // 2 x 2,097,152 floats
  conv_s1<ACT_RELU,8,2,2><<<dim3(B*8, 2, 2), blk, 0, stream>>>(bufA, dw[1], db[1], PD1, 64, 64, 32, 32, 2097152);
  combine2<ACT_RELU><<<dim3(2048), blk, 0, stream>>>(PD1, PD1 + 2097152, db[1], bufB, 64, 1024, 524288);

  tconv<ACT_RELU,4>      <<<dim3(B*8,  4), blk, 0, stream>>>(bufB, dw[2], db[2], bufA, 64, 32, 32);
  conv_s1<ACT_RELU,8,2,1><<<dim3(B*4,  8), blk, 0, stream>>>(bufA, dw[3], db[3], bufB, 32, 32, 64, 64, 0);
  tconv<ACT_RELU,8>      <<<dim3(B*2, 16), blk, 0, stream>>>(bufB, dw[4], db[4], bufA, 32, 16, 64);
  conv_s1<ACT_RELU,8,4,1><<<dim3(B*2, 16), blk, 0, stream>>>(bufA, dw[5], db[5], outp, 16, 16, 128, 128, 0);
}